// Round 10
// baseline (2972.119 us; speedup 1.0000x reference)
//
#include <hip/hip_runtime.h>
#include <math.h>

#define BB   64      // batch
#define TT   512     // time steps
#define CIN  32
#define THF  32
#define HH   1024    // hidden
#define LL   128
#define INF  64      // CIN + THF
#define KD   1088    // INF + HH
#define KP   1096    // bf16 Wt row stride (elems); 2192 B, 16B-aligned
#define SR2  1096    // fp32 fallback stride

typedef short  short8 __attribute__((ext_vector_type(8)));   // 8 bf16 = 4 VGPRs
typedef float  f32x4  __attribute__((ext_vector_type(4)));

static __device__ __forceinline__ unsigned short f2bf(float f) {   // RNE
    union { float f; unsigned u; } v; v.f = f;
    return (unsigned short)((v.u + 0x7fffu + ((v.u >> 16) & 1u)) >> 16);
}
static __device__ __forceinline__ float bf2f(unsigned short h) {
    union { unsigned u; float f; } v; v.u = ((unsigned)h) << 16;
    return v.f;
}

// ---------- one-time: W[KD][HH] fp32 -> Wt[HH][KP] bf16 (k-contiguous) ----------
__global__ __launch_bounds__(256)
void transposeW_bf16(const float* __restrict__ W, unsigned short* __restrict__ Wt) {
    __shared__ float tile[32][33];
    const int ct = blockIdx.x * 32;    // col tile
    const int kt = blockIdx.y * 32;    // k tile
    for (int i = threadIdx.y; i < 32; i += 8)
        tile[i][threadIdx.x] = W[(size_t)(kt + i) * HH + ct + threadIdx.x];
    __syncthreads();
    for (int i = threadIdx.y; i < 32; i += 8)
        Wt[(size_t)(ct + i) * KP + kt + threadIdx.x] = f2bf(tile[threadIdx.x][i]);
}

// ---------- per-step kernel: 1 wave = 1 full 16x16 output tile ----------
// grid 256 = 4 bg x 64 cg (bid%8 == cg%8 -> XCD-local W slice, 278 KB/XCD).
// 64 threads (one wave), NO LDS, NO barrier. Full K=1088 = 34 MFMAs in two
// interleaved acc chains. A row = batch b0+(lane&15); B row = col c0+(lane&15);
// D: col = lane&15, row = (lane>>4)*4 + reg.
__global__ __launch_bounds__(64)
void rnn_step4(const float* __restrict__ x, const float* __restrict__ tfeat,
               const unsigned short* __restrict__ Wt,    // [HH][KP] bf16
               const float* __restrict__ bias,
               const unsigned short* __restrict__ hprev, // [BB][HH] bf16
               unsigned short* __restrict__ hnext,       // [BB][HH] bf16
               int t)
{
    const int bid = blockIdx.x;
    const int bg  = bid >> 6, cg = bid & 63;
    const int b0  = bg * 16,  c0 = cg * 16;
    const int lane = threadIdx.x;
    const int l15 = lane & 15, lg = lane >> 4;

    const short8* brow = (const short8*)&Wt[(size_t)(c0 + l15) * KP];
    const short8* arow = (const short8*)(hprev + (size_t)(b0 + l15) * HH);

    f32x4 accA = {0.f, 0.f, 0.f, 0.f};
    f32x4 accB = {0.f, 0.f, 0.f, 0.f};

    // chunk 0 (k 0..31): x features, fp32 -> bf16 in-register
    {
        const float* xp = &x[((size_t)(b0 + l15) * TT + t) * CIN + lg * 8];
        float4 v0 = *(const float4*)xp, v1 = *(const float4*)(xp + 4);
        short8 a;
        a[0] = (short)f2bf(v0.x); a[1] = (short)f2bf(v0.y);
        a[2] = (short)f2bf(v0.z); a[3] = (short)f2bf(v0.w);
        a[4] = (short)f2bf(v1.x); a[5] = (short)f2bf(v1.y);
        a[6] = (short)f2bf(v1.z); a[7] = (short)f2bf(v1.w);
        accA = __builtin_amdgcn_mfma_f32_16x16x32_bf16(a, brow[0 * 4 + lg], accA, 0, 0, 0);
    }
    // chunk 1 (k 32..63): t features
    {
        const float* tp = &tfeat[((size_t)(b0 + l15) * TT + t) * THF + lg * 8];
        float4 v0 = *(const float4*)tp, v1 = *(const float4*)(tp + 4);
        short8 a;
        a[0] = (short)f2bf(v0.x); a[1] = (short)f2bf(v0.y);
        a[2] = (short)f2bf(v0.z); a[3] = (short)f2bf(v0.w);
        a[4] = (short)f2bf(v1.x); a[5] = (short)f2bf(v1.y);
        a[6] = (short)f2bf(v1.z); a[7] = (short)f2bf(v1.w);
        accB = __builtin_amdgcn_mfma_f32_16x16x32_bf16(a, brow[1 * 4 + lg], accB, 0, 0, 0);
    }
    // chunks 2..33 (k 64..1087): h region, bf16 direct; two interleaved chains
    #pragma unroll 4
    for (int i = 2; i < 34; i += 2) {
        accA = __builtin_amdgcn_mfma_f32_16x16x32_bf16(
                   arow[(i - 2) * 4 + lg], brow[i * 4 + lg], accA, 0, 0, 0);
        accB = __builtin_amdgcn_mfma_f32_16x16x32_bf16(
                   arow[(i - 1) * 4 + lg], brow[(i + 1) * 4 + lg], accB, 0, 0, 0);
    }

    const float bn = bias[c0 + l15];
    #pragma unroll
    for (int r = 0; r < 4; ++r) {
        float z = accA[r] + accB[r] + bn;
        hnext[(size_t)(b0 + lg * 4 + r) * HH + c0 + l15] = f2bf(tanhf(z));
    }
}

// ---------- epilogue (bf16 h) ----------
__global__ __launch_bounds__(128)
void rnn_out_bf16(const unsigned short* __restrict__ h, const float* __restrict__ Wout,
                  const float* __restrict__ bout, float* __restrict__ out)
{
    __shared__ float hl[HH];
    const int b = blockIdx.x, tid = threadIdx.x;
    {
        const short8* hp8 = (const short8*)(h + (size_t)b * HH);
        short8 v = hp8[tid];
        #pragma unroll
        for (int j = 0; j < 8; ++j) hl[tid * 8 + j] = bf2f((unsigned short)v[j]);
    }
    __syncthreads();
    float a0 = bout[tid], a1 = 0.f, a2 = 0.f, a3 = 0.f;
    for (int j = 0; j < HH; j += 4) {
        a0 = fmaf(hl[j + 0], Wout[(size_t)(j + 0) * LL + tid], a0);
        a1 = fmaf(hl[j + 1], Wout[(size_t)(j + 1) * LL + tid], a1);
        a2 = fmaf(hl[j + 2], Wout[(size_t)(j + 2) * LL + tid], a2);
        a3 = fmaf(hl[j + 3], Wout[(size_t)(j + 3) * LL + tid], a3);
    }
    out[(size_t)b * LL + tid] = (a0 + a1) + (a2 + a3);
}

// ================= fp32 fallback path (R7, proven) =================
__global__ __launch_bounds__(512, 2)
void rnn_step3(const float* __restrict__ x, const float* __restrict__ tfeat,
               const float* __restrict__ W, const float* __restrict__ bias,
               const float* __restrict__ hprev, float* __restrict__ hnext, int t)
{
    __shared__ float s[16 * SR2];
    __shared__ float zr[8][16][17];
    const int tid = threadIdx.x;
    const int bid = blockIdx.x;
    const int bg = bid >> 6, cg = bid & 63;
    const int b0 = bg * 16, c0 = cg * 16;
    const int q = tid >> 4, bb = (tid >> 2) & 3, cc = tid & 3;
    const int k0 = q * 36;

    const float4* hp4 = reinterpret_cast<const float4*>(hprev) + (size_t)b0 * 256;
    #pragma unroll
    for (int jj = 0; jj < 8; ++jj) {
        int f = tid + 512 * jj;
        int b = f >> 8, c = f & 255;
        float4 v = hp4[f];
        *reinterpret_cast<float4*>(&s[b * SR2 + INF + 4 * c]) = v;
    }
    if (tid < 256) {
        int b = tid >> 4, jf = tid & 15;
        float4 v;
        if (jf < 8) v = *reinterpret_cast<const float4*>(&x[((size_t)(b0 + b) * TT + t) * CIN + jf * 4]);
        else        v = *reinterpret_cast<const float4*>(&tfeat[((size_t)(b0 + b) * TT + t) * THF + (jf - 8) * 4]);
        *reinterpret_cast<float4*>(&s[b * SR2 + jf * 4]) = v;
    }
    __syncthreads();

    int nj = 0;
    if (k0 < KD) { int rem = KD - k0; nj = (rem >= 36) ? 9 : (rem >> 2); }
    const float* wp = W + (size_t)k0 * HH + c0 + 4 * cc;
    const float* sp = s + k0;
    float4 acc0 = {0,0,0,0}, acc1 = {0,0,0,0}, acc2 = {0,0,0,0}, acc3 = {0,0,0,0};
#define FMA4(A, sv, wv) \
    A.x = fmaf(sv, wv.x, A.x); A.y = fmaf(sv, wv.y, A.y); \
    A.z = fmaf(sv, wv.z, A.z); A.w = fmaf(sv, wv.w, A.w);
    #pragma unroll 2
    for (int j = 0; j < nj; ++j) {
        float4 w0 = *reinterpret_cast<const float4*>(wp + (size_t)(4 * j + 0) * HH);
        float4 w1 = *reinterpret_cast<const float4*>(wp + (size_t)(4 * j + 1) * HH);
        float4 w2 = *reinterpret_cast<const float4*>(wp + (size_t)(4 * j + 2) * HH);
        float4 w3 = *reinterpret_cast<const float4*>(wp + (size_t)(4 * j + 3) * HH);
        float4 s0 = *reinterpret_cast<const float4*>(sp + (bb +  0) * SR2 + 4 * j);
        float4 s1 = *reinterpret_cast<const float4*>(sp + (bb +  4) * SR2 + 4 * j);
        float4 s2 = *reinterpret_cast<const float4*>(sp + (bb +  8) * SR2 + 4 * j);
        float4 s3 = *reinterpret_cast<const float4*>(sp + (bb + 12) * SR2 + 4 * j);
        FMA4(acc0, s0.x, w0) FMA4(acc0, s0.y, w1) FMA4(acc0, s0.z, w2) FMA4(acc0, s0.w, w3)
        FMA4(acc1, s1.x, w0) FMA4(acc1, s1.y, w1) FMA4(acc1, s1.z, w2) FMA4(acc1, s1.w, w3)
        FMA4(acc2, s2.x, w0) FMA4(acc2, s2.y, w1) FMA4(acc2, s2.z, w2) FMA4(acc2, s2.w, w3)
        FMA4(acc3, s3.x, w0) FMA4(acc3, s3.y, w1) FMA4(acc3, s3.z, w2) FMA4(acc3, s3.w, w3)
    }
#undef FMA4
#define REDSTEP(A, D) \
    A.x += __shfl_xor(A.x, D); A.y += __shfl_xor(A.y, D); \
    A.z += __shfl_xor(A.z, D); A.w += __shfl_xor(A.w, D);
    REDSTEP(acc0, 16) REDSTEP(acc1, 16) REDSTEP(acc2, 16) REDSTEP(acc3, 16)
    REDSTEP(acc0, 32) REDSTEP(acc1, 32) REDSTEP(acc2, 32) REDSTEP(acc3, 32)
#undef REDSTEP
    if ((tid & 48) == 0) {
        int ww = tid >> 6;
        zr[ww][bb +  0][4*cc+0] = acc0.x; zr[ww][bb +  0][4*cc+1] = acc0.y;
        zr[ww][bb +  0][4*cc+2] = acc0.z; zr[ww][bb +  0][4*cc+3] = acc0.w;
        zr[ww][bb +  4][4*cc+0] = acc1.x; zr[ww][bb +  4][4*cc+1] = acc1.y;
        zr[ww][bb +  4][4*cc+2] = acc1.z; zr[ww][bb +  4][4*cc+3] = acc1.w;
        zr[ww][bb +  8][4*cc+0] = acc2.x; zr[ww][bb +  8][4*cc+1] = acc2.y;
        zr[ww][bb +  8][4*cc+2] = acc2.z; zr[ww][bb +  8][4*cc+3] = acc2.w;
        zr[ww][bb + 12][4*cc+0] = acc3.x; zr[ww][bb + 12][4*cc+1] = acc3.y;
        zr[ww][bb + 12][4*cc+2] = acc3.z; zr[ww][bb + 12][4*cc+3] = acc3.w;
    }
    __syncthreads();
    if (tid < 256) {
        int b = tid >> 4, c = tid & 15;
        float z = bias[c0 + c];
        #pragma unroll
        for (int g = 0; g < 8; ++g) z += zr[g][b][c];
        hnext[(size_t)(b0 + b) * HH + c0 + c] = tanhf(z);
    }
}

__global__ __launch_bounds__(128)
void rnn_out(const float* __restrict__ h, const float* __restrict__ Wout,
             const float* __restrict__ bout, float* __restrict__ out)
{
    __shared__ float hl[HH];
    const int b = blockIdx.x, tid = threadIdx.x;
    for (int i = tid; i < HH / 4; i += 128)
        *reinterpret_cast<float4*>(hl + 4 * i) =
            *reinterpret_cast<const float4*>(h + (size_t)b * HH + 4 * i);
    __syncthreads();
    float a0 = bout[tid], a1 = 0.f, a2 = 0.f, a3 = 0.f;
    for (int j = 0; j < HH; j += 4) {
        a0 = fmaf(hl[j + 0], Wout[(size_t)(j + 0) * LL + tid], a0);
        a1 = fmaf(hl[j + 1], Wout[(size_t)(j + 1) * LL + tid], a1);
        a2 = fmaf(hl[j + 2], Wout[(size_t)(j + 2) * LL + tid], a2);
        a3 = fmaf(hl[j + 3], Wout[(size_t)(j + 3) * LL + tid], a3);
    }
    out[(size_t)b * LL + tid] = (a0 + a1) + (a2 + a3);
}

__global__ __launch_bounds__(512)
void rnn_scan_kernel(const float* __restrict__ x, const float* __restrict__ tf,
                     const float* __restrict__ W, const float* __restrict__ bias,
                     const float* __restrict__ Wout, const float* __restrict__ bout,
                     float* __restrict__ out)
{
    __shared__ float s[KD];
    const int b_idx = blockIdx.x, tid = threadIdx.x;
    if (tid < CIN)      s[tid] = x[b_idx * TT * CIN + tid];
    else if (tid < INF) s[tid] = tf[b_idx * TT * THF + (tid - CIN)];
    for (int i = tid; i < HH; i += 512) s[INF + i] = 0.0f;
    __syncthreads();
    const int j0 = tid * 2;
    const float bias0 = bias[j0], bias1 = bias[j0 + 1];
    for (int t = 0; t < TT; ++t) {
        float z0 = bias0, z1 = bias1;
        #pragma unroll 8
        for (int k = 0; k < KD; ++k) {
            const float2 wv = *reinterpret_cast<const float2*>(&W[(size_t)k * HH + j0]);
            const float sv = s[k];
            z0 = fmaf(sv, wv.x, z0);
            z1 = fmaf(sv, wv.y, z1);
        }
        float nin = 0.0f;
        const int tn = t + 1;
        if (tn < TT) {
            if (tid < CIN)      nin = x[b_idx * TT * CIN + tn * CIN + tid];
            else if (tid < INF) nin = tf[b_idx * TT * THF + tn * THF + (tid - CIN)];
        }
        __syncthreads();
        s[INF + j0]     = tanhf(z0);
        s[INF + j0 + 1] = tanhf(z1);
        if (tid < INF && tn < TT) s[tid] = nin;
        __syncthreads();
    }
    for (int lll = tid; lll < LL; lll += 512) {
        float acc = bout[lll];
        for (int j = 0; j < HH; ++j) acc = fmaf(s[INF + j], Wout[(size_t)j * LL + lll], acc);
        out[(size_t)b_idx * LL + lll] = acc;
    }
}

extern "C" void kernel_launch(void* const* d_in, const int* in_sizes, int n_in,
                              void* d_out, int out_size, void* d_ws, size_t ws_size,
                              hipStream_t stream) {
    const float* x    = (const float*)d_in[0];   // [64, 512, 32]
    const float* tf   = (const float*)d_in[1];   // [64, 512, 32]
    const float* W    = (const float*)d_in[2];   // [1088, 1024]
    const float* brnn = (const float*)d_in[3];   // [1024]
    const float* Wout = (const float*)d_in[4];   // [1024, 128]
    const float* bout = (const float*)d_in[5];   // [128]
    float* out = (float*)d_out;                  // [64, 1, 128]

    // ---- MFMA bf16 path ----
    const size_t hbf_bytes = 2ull * BB * HH * sizeof(unsigned short);
    const size_t wt_bytes  = (size_t)HH * KP * sizeof(unsigned short);
    if (ws_size >= hbf_bytes + wt_bytes) {
        unsigned short* hbf = (unsigned short*)d_ws;
        unsigned short* Wt  = hbf + 2ull * BB * HH;
        hipMemsetAsync(hbf, 0, (size_t)BB * HH * sizeof(unsigned short), stream);
        transposeW_bf16<<<dim3(HH / 32, KD / 32), dim3(32, 8), 0, stream>>>(W, Wt);
        for (int t = 0; t < TT; ++t) {
            rnn_step4<<<256, 64, 0, stream>>>(x, tf, Wt, brnn,
                hbf + (size_t)(t & 1) * BB * HH,
                hbf + (size_t)((t + 1) & 1) * BB * HH, t);
        }
        rnn_out_bf16<<<BB, 128, 0, stream>>>(hbf /* parity 0 */, Wout, bout, out);
        return;
    }

    // ---- fp32 fallback (R7) ----
    float* hbuf = (float*)d_ws;
    const size_t hbuf_bytes = 2ull * BB * HH * sizeof(float);
    if (ws_size < hbuf_bytes) {
        rnn_scan_kernel<<<BB, 512, 0, stream>>>(x, tf, W, brnn, Wout, bout, out);
        return;
    }
    hipMemsetAsync(hbuf, 0, (size_t)BB * HH * sizeof(float), stream);
    for (int t = 0; t < TT; ++t) {
        rnn_step3<<<256, 512, 0, stream>>>(x, tf, W, brnn,
                                           hbuf + (size_t)(t & 1) * BB * HH,
                                           hbuf + (size_t)((t + 1) & 1) * BB * HH,
                                           t);
    }
    rnn_out<<<BB, 128, 0, stream>>>(hbuf, Wout, bout, out);
}

// Round 11
// 1866.693 us; speedup vs baseline: 1.5922x; 1.5922x over previous
//
#include <hip/hip_runtime.h>
#include <math.h>

#define BB   64      // batch
#define TT   512     // time steps
#define CIN  32
#define THF  32
#define HH   1024    // hidden
#define LL   128
#define INF  64      // CIN + THF
#define KD   1088    // INF + HH
#define KP   1096    // bf16 Wt row stride (elems); 2192 B, 16B-aligned
#define SR2  1096    // fp32 fallback stride

typedef short  short8 __attribute__((ext_vector_type(8)));   // 8 bf16 = 4 VGPRs
typedef float  f32x4  __attribute__((ext_vector_type(4)));

static __device__ __forceinline__ unsigned short f2bf(float f) {   // RNE
    union { float f; unsigned u; } v; v.f = f;
    return (unsigned short)((v.u + 0x7fffu + ((v.u >> 16) & 1u)) >> 16);
}
static __device__ __forceinline__ float bf2f(unsigned short h) {
    union { unsigned u; float f; } v; v.u = ((unsigned)h) << 16;
    return v.f;
}

// ---------- one-time: W[KD][HH] fp32 -> Wt[HH][KP] bf16 (k-contiguous) ----------
__global__ __launch_bounds__(256)
void transposeW_bf16(const float* __restrict__ W, unsigned short* __restrict__ Wt) {
    __shared__ float tile[32][33];
    const int ct = blockIdx.x * 32;    // col tile
    const int kt = blockIdx.y * 32;    // k tile
    for (int i = threadIdx.y; i < 32; i += 8)
        tile[i][threadIdx.x] = W[(size_t)(kt + i) * HH + ct + threadIdx.x];
    __syncthreads();
    for (int i = threadIdx.y; i < 32; i += 8)
        Wt[(size_t)(ct + i) * KP + kt + threadIdx.x] = f2bf(tile[threadIdx.x][i]);
}

// ---------- per-wave K-chunk: all frags straight from global (L2-hot) ----------
// chunk c covers k = c*32..c*32+31. c==0 -> x (fp32->bf16), c==1 -> tfeat,
// c>=2 -> hprev bf16. A-frag lane row = b0+l15, 16B at k-offset lg*8.
template<int Start, int Count>
static __device__ __forceinline__ f32x4
waveK(const float* __restrict__ x, const float* __restrict__ tfeat,
      const unsigned short* __restrict__ hprev, const short8* __restrict__ brow,
      int b0, int l15, int lg, int t, f32x4 acc)
{
    short8 bf[Count], af[Count];
    #pragma unroll
    for (int i = 0; i < Count; ++i) bf[i] = brow[(Start + i) * 4 + lg];   // W frags
    #pragma unroll
    for (int i = 0; i < Count; ++i) {
        if (Start + i == 0) {            // k 0..31: x features, convert
            const float* xp = &x[((size_t)(b0 + l15) * TT + t) * CIN + lg * 8];
            float4 v0 = *(const float4*)xp, v1 = *(const float4*)(xp + 4);
            short8 a;
            a[0] = (short)f2bf(v0.x); a[1] = (short)f2bf(v0.y);
            a[2] = (short)f2bf(v0.z); a[3] = (short)f2bf(v0.w);
            a[4] = (short)f2bf(v1.x); a[5] = (short)f2bf(v1.y);
            a[6] = (short)f2bf(v1.z); a[7] = (short)f2bf(v1.w);
            af[i] = a;
        } else if (Start + i == 1) {     // k 32..63: t features, convert
            const float* tp = &tfeat[((size_t)(b0 + l15) * TT + t) * THF + lg * 8];
            float4 v0 = *(const float4*)tp, v1 = *(const float4*)(tp + 4);
            short8 a;
            a[0] = (short)f2bf(v0.x); a[1] = (short)f2bf(v0.y);
            a[2] = (short)f2bf(v0.z); a[3] = (short)f2bf(v0.w);
            a[4] = (short)f2bf(v1.x); a[5] = (short)f2bf(v1.y);
            a[6] = (short)f2bf(v1.z); a[7] = (short)f2bf(v1.w);
            af[i] = a;
        } else {                         // k>=64: h region, bf16 direct
            af[i] = ((const short8*)(hprev + (size_t)(b0 + l15) * HH))[(Start + i) * 4 + lg - 8];
        }
    }
    #pragma unroll
    for (int i = 0; i < Count; ++i)
        acc = __builtin_amdgcn_mfma_f32_16x16x32_bf16(af[i], bf[i], acc, 0, 0, 0);
    return acc;
}

// ---------- per-step MFMA kernel (R9 structure, proven 1.88 ms) ----------
// grid 256 = 4 bg x 64 cg (bid%8==cg%8 -> XCD-local W slice). 256 thr = 4 waves.
// Wave w owns K-chunks {0-8, 9-17, 18-25, 26-33}; 4-way reduce in LDS.
// R10 lesson: 4 waves/CU are the latency hiding — do NOT collapse to 1 wave.
__global__ __launch_bounds__(256)
void rnn_step_mfma(const float* __restrict__ x, const float* __restrict__ tfeat,
                   const unsigned short* __restrict__ Wt,    // [HH][KP] bf16
                   const float* __restrict__ bias,
                   const unsigned short* __restrict__ hprev, // [BB][HH] bf16
                   unsigned short* __restrict__ hnext,       // [BB][HH] bf16
                   int t)
{
    __shared__ float zr[4][16][16];

    const int tid = threadIdx.x;
    const int bid = blockIdx.x;
    const int bg  = bid >> 6, cg = bid & 63;
    const int b0  = bg * 16,  c0 = cg * 16;
    const int w   = tid >> 6, lane = tid & 63;
    const int l15 = lane & 15, lg = lane >> 4;

    // hoist reducer's bias load: overlaps the MFMA phase instead of following it
    const float bn = bias[c0 + (tid & 15)];

    const short8* brow = (const short8*)&Wt[(size_t)(c0 + l15) * KP];
    f32x4 acc = {0.f, 0.f, 0.f, 0.f};
    if      (w == 0) acc = waveK< 0, 9>(x, tfeat, hprev, brow, b0, l15, lg, t, acc);
    else if (w == 1) acc = waveK< 9, 9>(x, tfeat, hprev, brow, b0, l15, lg, t, acc);
    else if (w == 2) acc = waveK<18, 8>(x, tfeat, hprev, brow, b0, l15, lg, t, acc);
    else             acc = waveK<26, 8>(x, tfeat, hprev, brow, b0, l15, lg, t, acc);

    // D frag: col = l15, row = lg*4 + r
    #pragma unroll
    for (int r = 0; r < 4; ++r) zr[w][lg * 4 + r][l15] = acc[r];
    __syncthreads();

    // ---- 4-way reduce + bias + tanh + bf16 store (coalesced 16x16) ----
    {
        int b = tid >> 4, c = tid & 15;
        float z = bn + zr[0][b][c] + zr[1][b][c] + zr[2][b][c] + zr[3][b][c];
        hnext[(size_t)(b0 + b) * HH + c0 + c] = f2bf(tanhf(z));
    }
}

// ---------- epilogue (bf16 h) ----------
__global__ __launch_bounds__(128)
void rnn_out_bf16(const unsigned short* __restrict__ h, const float* __restrict__ Wout,
                  const float* __restrict__ bout, float* __restrict__ out)
{
    __shared__ float hl[HH];
    const int b = blockIdx.x, tid = threadIdx.x;
    {
        const short8* hp8 = (const short8*)(h + (size_t)b * HH);
        short8 v = hp8[tid];
        #pragma unroll
        for (int j = 0; j < 8; ++j) hl[tid * 8 + j] = bf2f((unsigned short)v[j]);
    }
    __syncthreads();
    float a0 = bout[tid], a1 = 0.f, a2 = 0.f, a3 = 0.f;
    for (int j = 0; j < HH; j += 4) {
        a0 = fmaf(hl[j + 0], Wout[(size_t)(j + 0) * LL + tid], a0);
        a1 = fmaf(hl[j + 1], Wout[(size_t)(j + 1) * LL + tid], a1);
        a2 = fmaf(hl[j + 2], Wout[(size_t)(j + 2) * LL + tid], a2);
        a3 = fmaf(hl[j + 3], Wout[(size_t)(j + 3) * LL + tid], a3);
    }
    out[(size_t)b * LL + tid] = (a0 + a1) + (a2 + a3);
}

// ================= fp32 fallback path (R7, proven) =================
__global__ __launch_bounds__(512, 2)
void rnn_step3(const float* __restrict__ x, const float* __restrict__ tfeat,
               const float* __restrict__ W, const float* __restrict__ bias,
               const float* __restrict__ hprev, float* __restrict__ hnext, int t)
{
    __shared__ float s[16 * SR2];
    __shared__ float zr[8][16][17];
    const int tid = threadIdx.x;
    const int bid = blockIdx.x;
    const int bg = bid >> 6, cg = bid & 63;
    const int b0 = bg * 16, c0 = cg * 16;
    const int q = tid >> 4, bb = (tid >> 2) & 3, cc = tid & 3;
    const int k0 = q * 36;

    const float4* hp4 = reinterpret_cast<const float4*>(hprev) + (size_t)b0 * 256;
    #pragma unroll
    for (int jj = 0; jj < 8; ++jj) {
        int f = tid + 512 * jj;
        int b = f >> 8, c = f & 255;
        float4 v = hp4[f];
        *reinterpret_cast<float4*>(&s[b * SR2 + INF + 4 * c]) = v;
    }
    if (tid < 256) {
        int b = tid >> 4, jf = tid & 15;
        float4 v;
        if (jf < 8) v = *reinterpret_cast<const float4*>(&x[((size_t)(b0 + b) * TT + t) * CIN + jf * 4]);
        else        v = *reinterpret_cast<const float4*>(&tfeat[((size_t)(b0 + b) * TT + t) * THF + (jf - 8) * 4]);
        *reinterpret_cast<float4*>(&s[b * SR2 + jf * 4]) = v;
    }
    __syncthreads();

    int nj = 0;
    if (k0 < KD) { int rem = KD - k0; nj = (rem >= 36) ? 9 : (rem >> 2); }
    const float* wp = W + (size_t)k0 * HH + c0 + 4 * cc;
    const float* sp = s + k0;
    float4 acc0 = {0,0,0,0}, acc1 = {0,0,0,0}, acc2 = {0,0,0,0}, acc3 = {0,0,0,0};
#define FMA4(A, sv, wv) \
    A.x = fmaf(sv, wv.x, A.x); A.y = fmaf(sv, wv.y, A.y); \
    A.z = fmaf(sv, wv.z, A.z); A.w = fmaf(sv, wv.w, A.w);
    #pragma unroll 2
    for (int j = 0; j < nj; ++j) {
        float4 w0 = *reinterpret_cast<const float4*>(wp + (size_t)(4 * j + 0) * HH);
        float4 w1 = *reinterpret_cast<const float4*>(wp + (size_t)(4 * j + 1) * HH);
        float4 w2 = *reinterpret_cast<const float4*>(wp + (size_t)(4 * j + 2) * HH);
        float4 w3 = *reinterpret_cast<const float4*>(wp + (size_t)(4 * j + 3) * HH);
        float4 s0 = *reinterpret_cast<const float4*>(sp + (bb +  0) * SR2 + 4 * j);
        float4 s1 = *reinterpret_cast<const float4*>(sp + (bb +  4) * SR2 + 4 * j);
        float4 s2 = *reinterpret_cast<const float4*>(sp + (bb +  8) * SR2 + 4 * j);
        float4 s3 = *reinterpret_cast<const float4*>(sp + (bb + 12) * SR2 + 4 * j);
        FMA4(acc0, s0.x, w0) FMA4(acc0, s0.y, w1) FMA4(acc0, s0.z, w2) FMA4(acc0, s0.w, w3)
        FMA4(acc1, s1.x, w0) FMA4(acc1, s1.y, w1) FMA4(acc1, s1.z, w2) FMA4(acc1, s1.w, w3)
        FMA4(acc2, s2.x, w0) FMA4(acc2, s2.y, w1) FMA4(acc2, s2.z, w2) FMA4(acc2, s2.w, w3)
        FMA4(acc3, s3.x, w0) FMA4(acc3, s3.y, w1) FMA4(acc3, s3.z, w2) FMA4(acc3, s3.w, w3)
    }
#undef FMA4
#define REDSTEP(A, D) \
    A.x += __shfl_xor(A.x, D); A.y += __shfl_xor(A.y, D); \
    A.z += __shfl_xor(A.z, D); A.w += __shfl_xor(A.w, D);
    REDSTEP(acc0, 16) REDSTEP(acc1, 16) REDSTEP(acc2, 16) REDSTEP(acc3, 16)
    REDSTEP(acc0, 32) REDSTEP(acc1, 32) REDSTEP(acc2, 32) REDSTEP(acc3, 32)
#undef REDSTEP
    if ((tid & 48) == 0) {
        int ww = tid >> 6;
        zr[ww][bb +  0][4*cc+0] = acc0.x; zr[ww][bb +  0][4*cc+1] = acc0.y;
        zr[ww][bb +  0][4*cc+2] = acc0.z; zr[ww][bb +  0][4*cc+3] = acc0.w;
        zr[ww][bb +  4][4*cc+0] = acc1.x; zr[ww][bb +  4][4*cc+1] = acc1.y;
        zr[ww][bb +  4][4*cc+2] = acc1.z; zr[ww][bb +  4][4*cc+3] = acc1.w;
        zr[ww][bb +  8][4*cc+0] = acc2.x; zr[ww][bb +  8][4*cc+1] = acc2.y;
        zr[ww][bb +  8][4*cc+2] = acc2.z; zr[ww][bb +  8][4*cc+3] = acc2.w;
        zr[ww][bb + 12][4*cc+0] = acc3.x; zr[ww][bb + 12][4*cc+1] = acc3.y;
        zr[ww][bb + 12][4*cc+2] = acc3.z; zr[ww][bb + 12][4*cc+3] = acc3.w;
    }
    __syncthreads();
    if (tid < 256) {
        int b = tid >> 4, c = tid & 15;
        float z = bias[c0 + c];
        #pragma unroll
        for (int g = 0; g < 8; ++g) z += zr[g][b][c];
        hnext[(size_t)(b0 + b) * HH + c0 + c] = tanhf(z);
    }
}

__global__ __launch_bounds__(128)
void rnn_out(const float* __restrict__ h, const float* __restrict__ Wout,
             const float* __restrict__ bout, float* __restrict__ out)
{
    __shared__ float hl[HH];
    const int b = blockIdx.x, tid = threadIdx.x;
    for (int i = tid; i < HH / 4; i += 128)
        *reinterpret_cast<float4*>(hl + 4 * i) =
            *reinterpret_cast<const float4*>(h + (size_t)b * HH + 4 * i);
    __syncthreads();
    float a0 = bout[tid], a1 = 0.f, a2 = 0.f, a3 = 0.f;
    for (int j = 0; j < HH; j += 4) {
        a0 = fmaf(hl[j + 0], Wout[(size_t)(j + 0) * LL + tid], a0);
        a1 = fmaf(hl[j + 1], Wout[(size_t)(j + 1) * LL + tid], a1);
        a2 = fmaf(hl[j + 2], Wout[(size_t)(j + 2) * LL + tid], a2);
        a3 = fmaf(hl[j + 3], Wout[(size_t)(j + 3) * LL + tid], a3);
    }
    out[(size_t)b * LL + tid] = (a0 + a1) + (a2 + a3);
}

__global__ __launch_bounds__(512)
void rnn_scan_kernel(const float* __restrict__ x, const float* __restrict__ tf,
                     const float* __restrict__ W, const float* __restrict__ bias,
                     const float* __restrict__ Wout, const float* __restrict__ bout,
                     float* __restrict__ out)
{
    __shared__ float s[KD];
    const int b_idx = blockIdx.x, tid = threadIdx.x;
    if (tid < CIN)      s[tid] = x[b_idx * TT * CIN + tid];
    else if (tid < INF) s[tid] = tf[b_idx * TT * THF + (tid - CIN)];
    for (int i = tid; i < HH; i += 512) s[INF + i] = 0.0f;
    __syncthreads();
    const int j0 = tid * 2;
    const float bias0 = bias[j0], bias1 = bias[j0 + 1];
    for (int t = 0; t < TT; ++t) {
        float z0 = bias0, z1 = bias1;
        #pragma unroll 8
        for (int k = 0; k < KD; ++k) {
            const float2 wv = *reinterpret_cast<const float2*>(&W[(size_t)k * HH + j0]);
            const float sv = s[k];
            z0 = fmaf(sv, wv.x, z0);
            z1 = fmaf(sv, wv.y, z1);
        }
        float nin = 0.0f;
        const int tn = t + 1;
        if (tn < TT) {
            if (tid < CIN)      nin = x[b_idx * TT * CIN + tn * CIN + tid];
            else if (tid < INF) nin = tf[b_idx * TT * THF + tn * THF + (tid - CIN)];
        }
        __syncthreads();
        s[INF + j0]     = tanhf(z0);
        s[INF + j0 + 1] = tanhf(z1);
        if (tid < INF && tn < TT) s[tid] = nin;
        __syncthreads();
    }
    for (int lll = tid; lll < LL; lll += 512) {
        float acc = bout[lll];
        for (int j = 0; j < HH; ++j) acc = fmaf(s[INF + j], Wout[(size_t)j * LL + lll], acc);
        out[(size_t)b_idx * LL + lll] = acc;
    }
}

extern "C" void kernel_launch(void* const* d_in, const int* in_sizes, int n_in,
                              void* d_out, int out_size, void* d_ws, size_t ws_size,
                              hipStream_t stream) {
    const float* x    = (const float*)d_in[0];   // [64, 512, 32]
    const float* tf   = (const float*)d_in[1];   // [64, 512, 32]
    const float* W    = (const float*)d_in[2];   // [1088, 1024]
    const float* brnn = (const float*)d_in[3];   // [1024]
    const float* Wout = (const float*)d_in[4];   // [1024, 128]
    const float* bout = (const float*)d_in[5];   // [128]
    float* out = (float*)d_out;                  // [64, 1, 128]

    // ---- MFMA bf16 path ----
    const size_t hbf_bytes = 2ull * BB * HH * sizeof(unsigned short);
    const size_t wt_bytes  = (size_t)HH * KP * sizeof(unsigned short);
    if (ws_size >= hbf_bytes + wt_bytes) {
        unsigned short* hbf = (unsigned short*)d_ws;
        unsigned short* Wt  = hbf + 2ull * BB * HH;
        hipMemsetAsync(hbf, 0, (size_t)BB * HH * sizeof(unsigned short), stream);
        transposeW_bf16<<<dim3(HH / 32, KD / 32), dim3(32, 8), 0, stream>>>(W, Wt);
        for (int t = 0; t < TT; ++t) {
            rnn_step_mfma<<<256, 256, 0, stream>>>(x, tf, Wt, brnn,
                hbf + (size_t)(t & 1) * BB * HH,
                hbf + (size_t)((t + 1) & 1) * BB * HH, t);
        }
        rnn_out_bf16<<<BB, 128, 0, stream>>>(hbf /* parity 0 */, Wout, bout, out);
        return;
    }

    // ---- fp32 fallback (R7) ----
    float* hbuf = (float*)d_ws;
    const size_t hbuf_bytes = 2ull * BB * HH * sizeof(float);
    if (ws_size < hbuf_bytes) {
        rnn_scan_kernel<<<BB, 512, 0, stream>>>(x, tf, W, brnn, Wout, bout, out);
        return;
    }
    hipMemsetAsync(hbuf, 0, (size_t)BB * HH * sizeof(float), stream);
    for (int t = 0; t < TT; ++t) {
        rnn_step3<<<256, 512, 0, stream>>>(x, tf, W, brnn,
                                           hbuf + (size_t)(t & 1) * BB * HH,
                                           hbuf + (size_t)((t + 1) & 1) * BB * HH,
                                           t);
    }
    rnn_out<<<BB, 128, 0, stream>>>(hbuf, Wout, bout, out);
}